// Round 3
// baseline (23373.729 us; speedup 1.0000x reference)
//
#include <hip/hip_runtime.h>
#include <hip/hip_bf16.h>
#include <hip/hip_cooperative_groups.h>
#include <math.h>

#define B   64
#define T   256
#define H   1024
#define G4  4096
#define TC  64            // timesteps per x_proj chunk
#define NCH (T / TC)

typedef __attribute__((ext_vector_type(8))) short bf16x8;
typedef __attribute__((ext_vector_type(4))) float f32x4;

__device__ __forceinline__ unsigned short f2bf(float x) {
    union { float f; unsigned u; } v; v.f = x;
    unsigned r = v.u + 0x7fffu + ((v.u >> 16) & 1u);   // RNE
    return (unsigned short)(r >> 16);
}
__device__ __forceinline__ float bf2f(unsigned short s) {
    union { unsigned u; float f; } v; v.u = ((unsigned)s) << 16;
    return v.f;
}

// ---------------------------------------------------------------------------
__global__ __launch_bounds__(256) void cast_f32_bf16(
    const float* __restrict__ src, unsigned short* __restrict__ dst, int n8)
{
    int i = blockIdx.x * 256 + threadIdx.x;
    if (i >= n8) return;
    const float4* s = (const float4*)(src + (size_t)i * 8);
    float4 a = s[0], b = s[1];
    bf16x8 o;
    o[0] = f2bf(a.x); o[1] = f2bf(a.y); o[2] = f2bf(a.z); o[3] = f2bf(a.w);
    o[4] = f2bf(b.x); o[5] = f2bf(b.y); o[6] = f2bf(b.z); o[7] = f2bf(b.w);
    *(bf16x8*)(dst + (size_t)i * 8) = o;
}

// ---------------------------------------------------------------------------
__global__ __launch_bounds__(256) void gather_x(
    const int* __restrict__ tgt, const float* __restrict__ emb,
    unsigned short* __restrict__ xch, int t0)
{
    int tid = threadIdx.x;
    int r   = blockIdx.x * 2 + (tid >> 7);     // 0..4095
    int c   = (tid & 127) * 8;
    int b   = r & 63, tcc = r >> 6;
    int token = tgt[b * T + t0 + tcc];
    const float4* s = (const float4*)(emb + (size_t)token * H + c);
    float4 x0 = s[0], x1 = s[1];
    bf16x8 o;
    o[0] = f2bf(x0.x); o[1] = f2bf(x0.y); o[2] = f2bf(x0.z); o[3] = f2bf(x0.w);
    o[4] = f2bf(x1.x); o[5] = f2bf(x1.y); o[6] = f2bf(x1.z); o[7] = f2bf(x1.w);
    *(bf16x8*)(xch + (size_t)r * H + c) = o;
}

// ---------------------------------------------------------------------------
// x_proj chunk GEMM (unchanged from passing round 2)
// ---------------------------------------------------------------------------
__global__ __launch_bounds__(256) void gemm_xproj(
    const unsigned short* __restrict__ A,   // x chunk bf16 [4096][1024]
    const unsigned short* __restrict__ Bt,  // W_ih bf16 [4096][1024]
    unsigned short* __restrict__ C)         // [4096][4096]
{
    __shared__ unsigned short As[128 * 64], Bs[128 * 64];
    const int tid  = threadIdx.x;
    const int brow = (blockIdx.x >> 5) * 128;
    const int bcol = (blockIdx.x & 31) * 128;
    const int w = tid >> 6, lane = tid & 63;
    const int wr = w >> 1, wc = w & 1;
    const int lr = lane & 15, lg = lane >> 4;

    f32x4 acc[4][4] = {};

    for (int kc = 0; kc < H; kc += 64) {
        if (kc) __syncthreads();
        #pragma unroll
        for (int i = 0; i < 4; ++i) {
            int sf  = i * 256 + tid;
            int row = sf >> 3, s = sf & 7;
            int col = kc + s * 8;
            *(bf16x8*)(As + row * 64 + ((s ^ (row & 7)) * 8)) =
                *(const bf16x8*)(A + (size_t)(brow + row) * H + col);
            *(bf16x8*)(Bs + row * 64 + ((s ^ (row & 7)) * 8)) =
                *(const bf16x8*)(Bt + (size_t)(bcol + row) * H + col);
        }
        __syncthreads();
        #pragma unroll
        for (int kk = 0; kk < 2; ++kk) {
            bf16x8 af[4], bv[4];
            #pragma unroll
            for (int m = 0; m < 4; ++m) {
                int row = wr * 64 + m * 16 + lr;
                int s   = kk * 4 + lg;
                af[m] = *(const bf16x8*)(As + row * 64 + ((s ^ (row & 7)) * 8));
            }
            #pragma unroll
            for (int n = 0; n < 4; ++n) {
                int row = wc * 64 + n * 16 + lr;
                int s   = kk * 4 + lg;
                bv[n] = *(const bf16x8*)(Bs + row * 64 + ((s ^ (row & 7)) * 8));
            }
            #pragma unroll
            for (int m = 0; m < 4; ++m)
                #pragma unroll
                for (int n = 0; n < 4; ++n)
                    acc[m][n] = __builtin_amdgcn_mfma_f32_16x16x32_bf16(
                        af[m], bv[n], acc[m][n], 0, 0, 0);
        }
    }
    #pragma unroll
    for (int m = 0; m < 4; ++m)
        #pragma unroll
        for (int n = 0; n < 4; ++n)
            #pragma unroll
            for (int r = 0; r < 4; ++r) {
                int row = brow + wr * 64 + m * 16 + lg * 4 + r;
                int col = bcol + wc * 64 + n * 16 + lr;
                C[(size_t)row * G4 + col] = f2bf(acc[m][n][r]);
            }
}

// ---------------------------------------------------------------------------
// persistent cooperative recurrence: TC steps per launch, grid.sync per step.
// 256 blocks x 512 thr. Block jb owns h-cols [4jb,4jb+4) x 4 gates = 16 W rows
// resident in LDS (XOR-swizzled). c is register-resident. Only cross-block
// state: ping-pong bf16 h buffers (fence + grid sync per step).
// ---------------------------------------------------------------------------
__global__ __launch_bounds__(512) void lstm_coop(
    const unsigned short* __restrict__ xproj, // [TC][B][4096] bf16
    const unsigned short* __restrict__ whh,   // [4096][1024] bf16
    const float* __restrict__ bih, const float* __restrict__ bhh,
    unsigned short* __restrict__ hb0, unsigned short* __restrict__ hb1,
    float* __restrict__ cbuf,                 // [B][H] f32
    float* __restrict__ outputs,              // [B][T][H] f32
    int t0)
{
    __shared__ unsigned short Ws[16 * 1024];  // 32 KB, swizzled 16B slots
    __shared__ float gst[2][64][17];          // [kh][batch][n16] partials
    __shared__ float bias_s[16];

    const int tid = threadIdx.x;
    const int jb  = blockIdx.x;               // 0..255

    // stage the block's 16 W_hh rows (row v: gate q=v>>2, col jc=v&3)
    #pragma unroll
    for (int it = 0; it < 4; ++it) {
        int f = it * 512 + tid;               // 16B-slot id, 0..2047
        int v = f >> 7, s = f & 127;
        int grow = (v >> 2) * H + jb * 4 + (v & 3);
        *(bf16x8*)(Ws + v * H + ((s ^ (v & 7)) * 8)) =
            *(const bf16x8*)(whh + (size_t)grow * H + s * 8);
    }
    if (tid < 16) {
        int grow = (tid >> 2) * H + jb * 4 + (tid & 3);
        bias_s[tid] = bih[grow] + bhh[grow];
    }

    // epilogue thread mapping (tid < 256): jc fast for 16B-granular I/O
    const int b_e  = tid >> 2;                // 0..63
    const int jc_e = tid & 3;
    const int hj_e = jb * 4 + jc_e;
    float creg = 0.f;
    if (tid < 256) creg = cbuf[b_e * H + hj_e];

    const int w = tid >> 6, lane = tid & 63;
    const int m = w & 3, kh = w >> 2;         // wave = (M-tile, K-half)
    const int lr = lane & 15, lg = lane >> 4;
    __syncthreads();

    cooperative_groups::grid_group grid = cooperative_groups::this_grid();

    for (int tcs = 0; tcs < TC; ++tcs) {
        const int t = t0 + tcs;
        const unsigned short* hr = (t & 1) ? hb1 : hb0;
        unsigned short*       hw = (t & 1) ? hb0 : hb1;

        f32x4 acc = {};
        #pragma unroll
        for (int ks = 0; ks < 16; ++ks) {
            int k0 = kh * 512 + ks * 32 + lg * 8;
            int s  = k0 >> 3;
            bf16x8 bw = *(const bf16x8*)(Ws + lr * H + ((s ^ (lr & 7)) * 8));
            bf16x8 am = *(const bf16x8*)(hr + (size_t)(m * 16 + lr) * H + k0);
            acc = __builtin_amdgcn_mfma_f32_16x16x32_bf16(am, bw, acc, 0, 0, 0);
        }
        #pragma unroll
        for (int r = 0; r < 4; ++r)
            gst[kh][m * 16 + lg * 4 + r][lr] = acc[r];
        __syncthreads();

        if (tid < 256) {
            const unsigned short* xp = xproj + ((size_t)tcs * B + b_e) * G4;
            float g[4];
            #pragma unroll
            for (int q = 0; q < 4; ++q) {
                int v = q * 4 + jc_e;
                g[q] = gst[0][b_e][v] + gst[1][b_e][v] + bias_s[v]
                     + bf2f(xp[q * H + hj_e]);
            }
            float ig = 1.f / (1.f + expf(-g[0]));
            float fg = 1.f / (1.f + expf(-g[1]));
            float gg = tanhf(g[2]);
            float og = 1.f / (1.f + expf(-g[3]));
            float cn = fg * creg + ig * gg;
            float hn = og * tanhf(cn);
            creg = cn;
            hw[b_e * H + hj_e] = f2bf(hn);
            outputs[((size_t)b_e * T + t) * H + hj_e] = hn;
        }
        __threadfence();
        grid.sync();
    }
    if (tid < 256) cbuf[b_e * H + hj_e] = creg;
}

// ---------------------------------------------------------------------------
__global__ __launch_bounds__(256) void init_state(
    const float* __restrict__ h0, const float* __restrict__ c0,
    unsigned short* __restrict__ hb, float* __restrict__ cb)
{
    int i = blockIdx.x * 256 + threadIdx.x;
    hb[i] = f2bf(h0[i]);
    cb[i] = c0[i];
}

__global__ __launch_bounds__(256) void finalize(
    const float* __restrict__ outputs, const float* __restrict__ cfin,
    float* __restrict__ outh, float* __restrict__ outc)
{
    int i = blockIdx.x * 256 + threadIdx.x;     // 0..65535
    int b = i >> 10, j = i & 1023;
    outh[i] = outputs[((size_t)b * T + (T - 1)) * H + j];
    outc[i] = cfin[i];
}

// ---------------------------------------------------------------------------
extern "C" void kernel_launch(void* const* d_in, const int* in_sizes, int n_in,
                              void* d_out, int out_size, void* d_ws, size_t ws_size,
                              hipStream_t stream)
{
    const int*   tgt = (const int*)  d_in[0];
    const float* h0  = (const float*)d_in[1];
    const float* c0  = (const float*)d_in[2];
    const float* emb = (const float*)d_in[5];
    const float* Wih = (const float*)d_in[6];
    const float* Whh = (const float*)d_in[7];
    const float* bih = (const float*)d_in[8];
    const float* bhh = (const float*)d_in[9];

    float* out     = (float*)d_out;
    float* outputs = out;                                  // [B][T][H]
    float* out_h   = out + (size_t)B * T * H;
    float* out_c   = out_h + B * H;

    // ws layout — ~59.5 MB
    unsigned short* xproj = (unsigned short*)d_ws;          // TC*B*G4
    unsigned short* xch   = xproj + (size_t)TC * B * G4;    // (TC*B)*H
    unsigned short* wih   = xch   + (size_t)TC * B * H;     // G4*H
    unsigned short* whh   = wih   + (size_t)G4 * H;         // G4*H
    unsigned short* hb0   = whh   + (size_t)G4 * H;         // B*H
    unsigned short* hb1   = hb0   + (size_t)B * H;
    float*          cbuf  = (float*)(hb1 + (size_t)B * H);  // B*H f32

    cast_f32_bf16<<<2048, 256, 0, stream>>>(Wih, wih, (G4 * H) / 8);
    cast_f32_bf16<<<2048, 256, 0, stream>>>(Whh, whh, (G4 * H) / 8);
    init_state<<<(B * H) / 256, 256, 0, stream>>>(h0, c0, hb0, cbuf);

    for (int ci = 0; ci < NCH; ++ci) {
        gather_x<<<(TC * B) / 2, 256, 0, stream>>>(tgt, emb, xch, ci * TC);
        gemm_xproj<<<(TC * B / 128) * (G4 / 128), 256, 0, stream>>>(xch, wih, xproj);
        int t0 = ci * TC;
        void* args[] = { (void*)&xproj, (void*)&whh, (void*)&bih, (void*)&bhh,
                         (void*)&hb0, (void*)&hb1, (void*)&cbuf,
                         (void*)&outputs, (void*)&t0 };
        hipLaunchCooperativeKernel((void*)lstm_coop, dim3(256), dim3(512),
                                   args, 0, stream);
    }
    finalize<<<(B * H) / 256, 256, 0, stream>>>(outputs, cbuf, out_h, out_c);
}

// Round 4
// 8159.575 us; speedup vs baseline: 2.8646x; 2.8646x over previous
//
#include <hip/hip_runtime.h>
#include <hip/hip_bf16.h>
#include <math.h>

#define B   64
#define T   256
#define H   1024
#define G4  4096
#define TC  64            // timesteps per x_proj chunk
#define NCH (T / TC)

typedef __attribute__((ext_vector_type(8))) short bf16x8;
typedef __attribute__((ext_vector_type(4))) float f32x4;

__device__ __forceinline__ unsigned short f2bf(float x) {
    union { float f; unsigned u; } v; v.f = x;
    unsigned r = v.u + 0x7fffu + ((v.u >> 16) & 1u);   // RNE
    return (unsigned short)(r >> 16);
}
__device__ __forceinline__ float bf2f(unsigned short s) {
    union { unsigned u; float f; } v; v.u = ((unsigned)s) << 16;
    return v.f;
}

// ---------------------------------------------------------------------------
__global__ __launch_bounds__(256) void cast_f32_bf16(
    const float* __restrict__ src, unsigned short* __restrict__ dst, int n8)
{
    int i = blockIdx.x * 256 + threadIdx.x;
    if (i >= n8) return;
    const float4* s = (const float4*)(src + (size_t)i * 8);
    float4 a = s[0], b = s[1];
    bf16x8 o;
    o[0] = f2bf(a.x); o[1] = f2bf(a.y); o[2] = f2bf(a.z); o[3] = f2bf(a.w);
    o[4] = f2bf(b.x); o[5] = f2bf(b.y); o[6] = f2bf(b.z); o[7] = f2bf(b.w);
    *(bf16x8*)(dst + (size_t)i * 8) = o;
}

// ---------------------------------------------------------------------------
__global__ __launch_bounds__(256) void gather_x(
    const int* __restrict__ tgt, const float* __restrict__ emb,
    unsigned short* __restrict__ xch, int t0)
{
    int tid = threadIdx.x;
    int r   = blockIdx.x * 2 + (tid >> 7);     // 0..4095
    int c   = (tid & 127) * 8;
    int b   = r & 63, tcc = r >> 6;
    int token = tgt[b * T + t0 + tcc];
    const float4* s = (const float4*)(emb + (size_t)token * H + c);
    float4 x0 = s[0], x1 = s[1];
    bf16x8 o;
    o[0] = f2bf(x0.x); o[1] = f2bf(x0.y); o[2] = f2bf(x0.z); o[3] = f2bf(x0.w);
    o[4] = f2bf(x1.x); o[5] = f2bf(x1.y); o[6] = f2bf(x1.z); o[7] = f2bf(x1.w);
    *(bf16x8*)(xch + (size_t)r * H + c) = o;
}

// ---------------------------------------------------------------------------
// x_proj chunk GEMM (unchanged — proven in round 2)
// ---------------------------------------------------------------------------
__global__ __launch_bounds__(256) void gemm_xproj(
    const unsigned short* __restrict__ A,   // x chunk bf16 [4096][1024]
    const unsigned short* __restrict__ Bt,  // W_ih bf16 [4096][1024]
    unsigned short* __restrict__ C)         // [4096][4096]
{
    __shared__ unsigned short As[128 * 64], Bs[128 * 64];
    const int tid  = threadIdx.x;
    const int brow = (blockIdx.x >> 5) * 128;
    const int bcol = (blockIdx.x & 31) * 128;
    const int w = tid >> 6, lane = tid & 63;
    const int wr = w >> 1, wc = w & 1;
    const int lr = lane & 15, lg = lane >> 4;

    f32x4 acc[4][4] = {};

    for (int kc = 0; kc < H; kc += 64) {
        if (kc) __syncthreads();
        #pragma unroll
        for (int i = 0; i < 4; ++i) {
            int sf  = i * 256 + tid;
            int row = sf >> 3, s = sf & 7;
            int col = kc + s * 8;
            *(bf16x8*)(As + row * 64 + ((s ^ (row & 7)) * 8)) =
                *(const bf16x8*)(A + (size_t)(brow + row) * H + col);
            *(bf16x8*)(Bs + row * 64 + ((s ^ (row & 7)) * 8)) =
                *(const bf16x8*)(Bt + (size_t)(bcol + row) * H + col);
        }
        __syncthreads();
        #pragma unroll
        for (int kk = 0; kk < 2; ++kk) {
            bf16x8 af[4], bv[4];
            #pragma unroll
            for (int m = 0; m < 4; ++m) {
                int row = wr * 64 + m * 16 + lr;
                int s   = kk * 4 + lg;
                af[m] = *(const bf16x8*)(As + row * 64 + ((s ^ (row & 7)) * 8));
            }
            #pragma unroll
            for (int n = 0; n < 4; ++n) {
                int row = wc * 64 + n * 16 + lr;
                int s   = kk * 4 + lg;
                bv[n] = *(const bf16x8*)(Bs + row * 64 + ((s ^ (row & 7)) * 8));
            }
            #pragma unroll
            for (int m = 0; m < 4; ++m)
                #pragma unroll
                for (int n = 0; n < 4; ++n)
                    acc[m][n] = __builtin_amdgcn_mfma_f32_16x16x32_bf16(
                        af[m], bv[n], acc[m][n], 0, 0, 0);
        }
    }
    #pragma unroll
    for (int m = 0; m < 4; ++m)
        #pragma unroll
        for (int n = 0; n < 4; ++n)
            #pragma unroll
            for (int r = 0; r < 4; ++r) {
                int row = brow + wr * 64 + m * 16 + lg * 4 + r;
                int col = bcol + wc * 64 + n * 16 + lr;
                C[(size_t)row * G4 + col] = f2bf(acc[m][n][r]);
            }
}

// ---------------------------------------------------------------------------
// one LSTM step. 64 blocks x 1024 thr (16 waves = 4/SIMD for latency hiding).
// Block owns 16 h-cols (j0..j0+15) x 4 gates. Wave = (gate q, m-tile m):
// computes one 16x16 gate tile over FULL K=1024 (32 MFMA, no K-split, no
// partial-sum reduction). One barrier, then 1 thread = 1 (b,j) cell update.
// ---------------------------------------------------------------------------
__global__ __launch_bounds__(1024) void lstm_step(
    const unsigned short* __restrict__ xproj,  // [TC][B][4096] bf16
    const unsigned short* __restrict__ hin,    // [B][H] bf16
    const unsigned short* __restrict__ whh,    // [4096][1024] bf16
    const float* __restrict__ bih, const float* __restrict__ bhh,
    const float* __restrict__ cin, float* __restrict__ cout,
    unsigned short* __restrict__ hout,
    float* __restrict__ outputs, int t, int tc)
{
    __shared__ float red[4][64][17];    // [gate][batch][jc] final gate tiles
    __shared__ float bias_s[64];        // [gate*16 + jc]

    const int tid = threadIdx.x;
    const int j0  = blockIdx.x * 16;
    const int w = tid >> 6, lane = tid & 63;
    const int q = w >> 2, m = w & 3;
    const int lr = lane & 15, lg = lane >> 4;

    if (tid < 64) {
        int n = (tid >> 4) * H + j0 + (tid & 15);
        bias_s[tid] = bih[n] + bhh[n];
    }

    f32x4 acc = {};
    const unsigned short* wrow = whh + (size_t)(q * H + j0 + lr) * H;
    const unsigned short* arow = hin + (size_t)(m * 16 + lr) * H;
    #pragma unroll 8
    for (int ks = 0; ks < 32; ++ks) {
        int k0 = ks * 32 + lg * 8;
        bf16x8 bw = *(const bf16x8*)(wrow + k0);
        bf16x8 am = *(const bf16x8*)(arow + k0);
        acc = __builtin_amdgcn_mfma_f32_16x16x32_bf16(am, bw, acc, 0, 0, 0);
    }
    #pragma unroll
    for (int r = 0; r < 4; ++r)
        red[q][m * 16 + lg * 4 + r][lr] = acc[r];
    __syncthreads();

    // epilogue: thread -> (b = tid>>4, jc = tid&15)
    const int b  = tid >> 4;
    const int jc = tid & 15;
    const int hj = j0 + jc;
    const unsigned short* xp = xproj + ((size_t)tc * B + b) * G4;
    float g[4];
    #pragma unroll
    for (int qq = 0; qq < 4; ++qq)
        g[qq] = red[qq][b][jc] + bias_s[qq * 16 + jc] + bf2f(xp[qq * H + hj]);

    float ig = 1.f / (1.f + expf(-g[0]));
    float fg = 1.f / (1.f + expf(-g[1]));
    float gg = tanhf(g[2]);
    float og = 1.f / (1.f + expf(-g[3]));
    float cp = cin[b * H + hj];
    float cn = fg * cp + ig * gg;
    float hn = og * tanhf(cn);
    cout[b * H + hj] = cn;
    hout[b * H + hj] = f2bf(hn);
    outputs[((size_t)b * T + t) * H + hj] = hn;
}

// ---------------------------------------------------------------------------
__global__ __launch_bounds__(256) void init_state(
    const float* __restrict__ h0, const float* __restrict__ c0,
    unsigned short* __restrict__ hb, float* __restrict__ cb)
{
    int i = blockIdx.x * 256 + threadIdx.x;
    hb[i] = f2bf(h0[i]);
    cb[i] = c0[i];
}

__global__ __launch_bounds__(256) void finalize(
    const float* __restrict__ outputs, const float* __restrict__ cfin,
    float* __restrict__ outh, float* __restrict__ outc)
{
    int i = blockIdx.x * 256 + threadIdx.x;     // 0..65535
    int b = i >> 10, j = i & 1023;
    outh[i] = outputs[((size_t)b * T + (T - 1)) * H + j];
    outc[i] = cfin[i];
}

// ---------------------------------------------------------------------------
extern "C" void kernel_launch(void* const* d_in, const int* in_sizes, int n_in,
                              void* d_out, int out_size, void* d_ws, size_t ws_size,
                              hipStream_t stream)
{
    const int*   tgt = (const int*)  d_in[0];
    const float* h0  = (const float*)d_in[1];
    const float* c0  = (const float*)d_in[2];
    const float* emb = (const float*)d_in[5];
    const float* Wih = (const float*)d_in[6];
    const float* Whh = (const float*)d_in[7];
    const float* bih = (const float*)d_in[8];
    const float* bhh = (const float*)d_in[9];

    float* out     = (float*)d_out;
    float* outputs = out;                                  // [B][T][H]
    float* out_h   = out + (size_t)B * T * H;
    float* out_c   = out_h + B * H;

    // ws layout — ~59.5 MB
    unsigned short* xproj = (unsigned short*)d_ws;          // TC*B*G4
    unsigned short* xch   = xproj + (size_t)TC * B * G4;    // (TC*B)*H
    unsigned short* wih   = xch   + (size_t)TC * B * H;     // G4*H
    unsigned short* whh   = wih   + (size_t)G4 * H;         // G4*H
    unsigned short* hb0   = whh   + (size_t)G4 * H;         // B*H
    unsigned short* hb1   = hb0   + (size_t)B * H;
    float*          cb0   = (float*)(hb1 + (size_t)B * H);
    float*          cb1   = cb0 + (size_t)B * H;

    cast_f32_bf16<<<2048, 256, 0, stream>>>(Wih, wih, (G4 * H) / 8);
    cast_f32_bf16<<<2048, 256, 0, stream>>>(Whh, whh, (G4 * H) / 8);
    init_state<<<(B * H) / 256, 256, 0, stream>>>(h0, c0, hb0, cb0);

    for (int ci = 0; ci < NCH; ++ci) {
        gather_x<<<(TC * B) / 2, 256, 0, stream>>>(tgt, emb, xch, ci * TC);
        gemm_xproj<<<(TC * B / 128) * (G4 / 128), 256, 0, stream>>>(xch, wih, xproj);
        for (int tcs = 0; tcs < TC; ++tcs) {
            int t = ci * TC + tcs;
            lstm_step<<<H / 16, 1024, 0, stream>>>(
                xproj,
                (t & 1) ? hb1 : hb0, whh, bih, bhh,
                (t & 1) ? cb1 : cb0, (t & 1) ? cb0 : cb1,
                (t & 1) ? hb0 : hb1,
                outputs, t, tcs);
        }
    }
    finalize<<<(B * H) / 256, 256, 0, stream>>>(outputs, cb0, out_h, out_c);
}

// Round 5
// 2797.410 us; speedup vs baseline: 8.3555x; 2.9168x over previous
//
#include <hip/hip_runtime.h>
#include <hip/hip_bf16.h>
#include <math.h>

#define B    64
#define T    256
#define H    1024
#define G4   4096
#define TC   64           // timesteps per x_proj chunk
#define NCH  (T / TC)
#define NBLK 128          // persistent blocks (8 h-cols each)
#define FSTR 16           // flag stride in ints (64B apart)

typedef __attribute__((ext_vector_type(8))) short bf16x8;
typedef __attribute__((ext_vector_type(4))) float f32x4;

__device__ __forceinline__ unsigned short f2bf(float x) {
    union { float f; unsigned u; } v; v.f = x;
    unsigned r = v.u + 0x7fffu + ((v.u >> 16) & 1u);   // RNE
    return (unsigned short)(r >> 16);
}
__device__ __forceinline__ float bf2f(unsigned short s) {
    union { unsigned u; float f; } v; v.u = ((unsigned)s) << 16;
    return v.f;
}

// ---------------------------------------------------------------------------
__global__ __launch_bounds__(256) void cast_f32_bf16(
    const float* __restrict__ src, unsigned short* __restrict__ dst, int n8)
{
    int i = blockIdx.x * 256 + threadIdx.x;
    if (i >= n8) return;
    const float4* s = (const float4*)(src + (size_t)i * 8);
    float4 a = s[0], b = s[1];
    bf16x8 o;
    o[0] = f2bf(a.x); o[1] = f2bf(a.y); o[2] = f2bf(a.z); o[3] = f2bf(a.w);
    o[4] = f2bf(b.x); o[5] = f2bf(b.y); o[6] = f2bf(b.z); o[7] = f2bf(b.w);
    *(bf16x8*)(dst + (size_t)i * 8) = o;
}

// ---------------------------------------------------------------------------
__global__ __launch_bounds__(256) void gather_x(
    const int* __restrict__ tgt, const float* __restrict__ emb,
    unsigned short* __restrict__ xch, int t0)
{
    int tid = threadIdx.x;
    int r   = blockIdx.x * 2 + (tid >> 7);     // 0..4095
    int c   = (tid & 127) * 8;
    int b   = r & 63, tcc = r >> 6;
    int token = tgt[b * T + t0 + tcc];
    const float4* s = (const float4*)(emb + (size_t)token * H + c);
    float4 x0 = s[0], x1 = s[1];
    bf16x8 o;
    o[0] = f2bf(x0.x); o[1] = f2bf(x0.y); o[2] = f2bf(x0.z); o[3] = f2bf(x0.w);
    o[4] = f2bf(x1.x); o[5] = f2bf(x1.y); o[6] = f2bf(x1.z); o[7] = f2bf(x1.w);
    *(bf16x8*)(xch + (size_t)r * H + c) = o;
}

// ---------------------------------------------------------------------------
// x_proj chunk GEMM (unchanged — proven since round 2)
// ---------------------------------------------------------------------------
__global__ __launch_bounds__(256) void gemm_xproj(
    const unsigned short* __restrict__ A,   // x chunk bf16 [4096][1024]
    const unsigned short* __restrict__ Bt,  // W_ih bf16 [4096][1024]
    unsigned short* __restrict__ C)         // [4096][4096]
{
    __shared__ unsigned short As[128 * 64], Bs[128 * 64];
    const int tid  = threadIdx.x;
    const int brow = (blockIdx.x >> 5) * 128;
    const int bcol = (blockIdx.x & 31) * 128;
    const int w = tid >> 6, lane = tid & 63;
    const int wr = w >> 1, wc = w & 1;
    const int lr = lane & 15, lg = lane >> 4;

    f32x4 acc[4][4] = {};

    for (int kc = 0; kc < H; kc += 64) {
        if (kc) __syncthreads();
        #pragma unroll
        for (int i = 0; i < 4; ++i) {
            int sf  = i * 256 + tid;
            int row = sf >> 3, s = sf & 7;
            int col = kc + s * 8;
            *(bf16x8*)(As + row * 64 + ((s ^ (row & 7)) * 8)) =
                *(const bf16x8*)(A + (size_t)(brow + row) * H + col);
            *(bf16x8*)(Bs + row * 64 + ((s ^ (row & 7)) * 8)) =
                *(const bf16x8*)(Bt + (size_t)(bcol + row) * H + col);
        }
        __syncthreads();
        #pragma unroll
        for (int kk = 0; kk < 2; ++kk) {
            bf16x8 af[4], bv[4];
            #pragma unroll
            for (int m = 0; m < 4; ++m) {
                int row = wr * 64 + m * 16 + lr;
                int s   = kk * 4 + lg;
                af[m] = *(const bf16x8*)(As + row * 64 + ((s ^ (row & 7)) * 8));
            }
            #pragma unroll
            for (int n = 0; n < 4; ++n) {
                int row = wc * 64 + n * 16 + lr;
                int s   = kk * 4 + lg;
                bv[n] = *(const bf16x8*)(Bs + row * 64 + ((s ^ (row & 7)) * 8));
            }
            #pragma unroll
            for (int m = 0; m < 4; ++m)
                #pragma unroll
                for (int n = 0; n < 4; ++n)
                    acc[m][n] = __builtin_amdgcn_mfma_f32_16x16x32_bf16(
                        af[m], bv[n], acc[m][n], 0, 0, 0);
        }
    }
    #pragma unroll
    for (int m = 0; m < 4; ++m)
        #pragma unroll
        for (int n = 0; n < 4; ++n)
            #pragma unroll
            for (int r = 0; r < 4; ++r) {
                int row = brow + wr * 64 + m * 16 + lg * 4 + r;
                int col = bcol + wc * 64 + n * 16 + lr;
                C[(size_t)row * G4 + col] = f2bf(acc[m][n][r]);
            }
}

// ---------------------------------------------------------------------------
// persistent chunk recurrence. 128 blocks x 512 thr (cooperative launch for
// co-residency; NO grid.sync). Block jb owns h-cols [8jb,8jb+8) x 4 gates =
// 32 W_hh rows resident in LDS (XOR-swizzled). Per step: read h_{t} from a
// UNIQUE bf16 buffer (normal cached loads - lines never touched before, so
// never stale), MFMA 4 m-tiles x 2 n-tiles x K=1024, cell epilogue, publish
// h_{t+1} slice via agent-scope write-through stores, then flag = steps done.
// Readers spin on the 128 flags (relaxed agent atomic loads, wave 0 only).
// c is register-resident for the whole chunk.
// ---------------------------------------------------------------------------
__global__ __launch_bounds__(512) void lstm_chunk(
    const unsigned short* __restrict__ xproj,  // [TC][B][4096] bf16
    const unsigned short* __restrict__ whh,    // [4096][1024] bf16
    const float* __restrict__ bih, const float* __restrict__ bhh,
    unsigned short* __restrict__ hchain,       // [TC+1][B][H] bf16
    float* __restrict__ cbuf,                  // [B][H] f32
    float* __restrict__ outputs,               // [B][T][H] f32
    int* __restrict__ flags,                   // [NBLK*FSTR]
    int t0)
{
    __shared__ bf16x8 Ws[32 * 128];            // 64 KB, swizzled 16B slots
    __shared__ float  gst[64][34];             // gate tiles [batch][v=q*8+jc]
    __shared__ float  hsh[64][8];              // new h slice
    __shared__ float  bias_s[32];

    const int tid = threadIdx.x;
    const int jb  = blockIdx.x;
    const int j0  = jb * 8;

    // stage W_hh slice: rows v = q*8+jc -> global row q*H + j0 + jc
    #pragma unroll
    for (int it = 0; it < 8; ++it) {
        int f = it * 512 + tid;                // 16B-slot id, 0..4095
        int v = f >> 7, s = f & 127;
        int grow = (v >> 3) * H + j0 + (v & 7);
        Ws[v * 128 + (s ^ (v & 7))] =
            *(const bf16x8*)(whh + (size_t)grow * H + s * 8);
    }
    if (tid < 32) {
        int grow = (tid >> 3) * H + j0 + (tid & 7);
        bias_s[tid] = bih[grow] + bhh[grow];
    }

    // epilogue mapping: thread -> (b, jc)
    const int b_e  = tid >> 3;
    const int jc_e = tid & 7;
    const int hj_e = j0 + jc_e;
    float creg = cbuf[b_e * H + hj_e];

    const int w = tid >> 6, lane = tid & 63;
    const int m = w & 3, nt = w >> 2;          // wave = (m-tile, n-tile)
    const int lr = lane & 15, lg = lane >> 4;
    const int vrow = nt * 16 + lr;             // W row this lane provides
    const int vx   = vrow & 7;
    __syncthreads();

    for (int tcs = 0; tcs < TC; ++tcs) {
        const int target = t0 + tcs;
        if (w == 0) {
            while (true) {
                int f1 = __hip_atomic_load(&flags[lane * FSTR],
                            __ATOMIC_RELAXED, __HIP_MEMORY_SCOPE_AGENT);
                int f2 = __hip_atomic_load(&flags[(64 + lane) * FSTR],
                            __ATOMIC_RELAXED, __HIP_MEMORY_SCOPE_AGENT);
                if (__all(f1 >= target && f2 >= target)) break;
                __builtin_amdgcn_s_sleep(1);
            }
        }
        __syncthreads();

        const unsigned short* hcur = hchain + (size_t)tcs * B * H;
        const unsigned short* arow = hcur + (size_t)(m * 16 + lr) * H;
        f32x4 acc = {};
        #pragma unroll 4
        for (int ks = 0; ks < 32; ++ks) {
            bf16x8 av = *(const bf16x8*)(arow + ks * 32 + lg * 8);
            bf16x8 bw = Ws[vrow * 128 + ((ks * 4 + lg) ^ vx)];
            acc = __builtin_amdgcn_mfma_f32_16x16x32_bf16(av, bw, acc, 0, 0, 0);
        }
        #pragma unroll
        for (int r = 0; r < 4; ++r)
            gst[m * 16 + lg * 4 + r][vrow] = acc[r];
        __syncthreads();

        // cell epilogue
        {
            const unsigned short* xp = xproj + ((size_t)tcs * B + b_e) * G4;
            float g[4];
            #pragma unroll
            for (int q = 0; q < 4; ++q)
                g[q] = gst[b_e][q * 8 + jc_e] + bias_s[q * 8 + jc_e]
                     + bf2f(xp[q * H + hj_e]);
            float ig = 1.f / (1.f + expf(-g[0]));
            float fg = 1.f / (1.f + expf(-g[1]));
            float gg = tanhf(g[2]);
            float og = 1.f / (1.f + expf(-g[3]));
            float cn = fg * creg + ig * gg;
            float hn = og * tanhf(cn);
            creg = cn;
            hsh[b_e][jc_e] = hn;
            outputs[((size_t)b_e * T + (t0 + tcs)) * H + hj_e] = hn;
        }
        __syncthreads();

        // publish h slice: write-through dword stores (2 bf16 each)
        if (tid < 256) {
            int bb = tid >> 2, p = tid & 3;
            unsigned u = (unsigned)f2bf(hsh[bb][2 * p])
                       | ((unsigned)f2bf(hsh[bb][2 * p + 1]) << 16);
            unsigned* dst = (unsigned*)(hchain + (size_t)(tcs + 1) * B * H
                                        + bb * H + j0 + 2 * p);
            __hip_atomic_store(dst, u, __ATOMIC_RELAXED,
                               __HIP_MEMORY_SCOPE_AGENT);
        }
        __syncthreads();   // drains vmcnt -> h slice visible at LLC

        if (tid == 0)
            __hip_atomic_store(&flags[jb * FSTR], target + 1,
                               __ATOMIC_RELAXED, __HIP_MEMORY_SCOPE_AGENT);
    }
    cbuf[b_e * H + hj_e] = creg;
}

// ---------------------------------------------------------------------------
__global__ __launch_bounds__(256) void init_state(
    const float* __restrict__ h0, const float* __restrict__ c0,
    unsigned short* __restrict__ hb, float* __restrict__ cb)
{
    int i = blockIdx.x * 256 + threadIdx.x;
    hb[i] = f2bf(h0[i]);
    cb[i] = c0[i];
}

__global__ __launch_bounds__(128) void reset_flags(int* __restrict__ flags)
{
    __hip_atomic_store(&flags[threadIdx.x * FSTR], 0,
                       __ATOMIC_RELAXED, __HIP_MEMORY_SCOPE_AGENT);
}

__global__ __launch_bounds__(256) void copy_h(
    const unsigned short* __restrict__ src, unsigned short* __restrict__ dst)
{
    int i = blockIdx.x * 256 + threadIdx.x;    // dword index
    ((unsigned*)dst)[i] = ((const unsigned*)src)[i];
}

__global__ __launch_bounds__(256) void finalize(
    const float* __restrict__ outputs, const float* __restrict__ cfin,
    float* __restrict__ outh, float* __restrict__ outc)
{
    int i = blockIdx.x * 256 + threadIdx.x;    // 0..65535
    int b = i >> 10, j = i & 1023;
    outh[i] = outputs[((size_t)b * T + (T - 1)) * H + j];
    outc[i] = cfin[i];
}

// ---------------------------------------------------------------------------
extern "C" void kernel_launch(void* const* d_in, const int* in_sizes, int n_in,
                              void* d_out, int out_size, void* d_ws, size_t ws_size,
                              hipStream_t stream)
{
    const int*   tgt = (const int*)  d_in[0];
    const float* h0  = (const float*)d_in[1];
    const float* c0  = (const float*)d_in[2];
    const float* emb = (const float*)d_in[5];
    const float* Wih = (const float*)d_in[6];
    const float* Whh = (const float*)d_in[7];
    const float* bih = (const float*)d_in[8];
    const float* bhh = (const float*)d_in[9];

    float* out     = (float*)d_out;
    float* outputs = out;                                  // [B][T][H]
    float* out_h   = out + (size_t)B * T * H;
    float* out_c   = out_h + B * H;

    // ws layout — ~56.5 MB
    unsigned short* xproj  = (unsigned short*)d_ws;            // TC*B*G4
    unsigned short* xch    = xproj  + (size_t)TC * B * G4;     // TC*B*H
    unsigned short* wih    = xch    + (size_t)TC * B * H;      // G4*H
    unsigned short* whh    = wih    + (size_t)G4 * H;          // G4*H
    unsigned short* hchain = whh    + (size_t)G4 * H;          // (TC+1)*B*H
    float*          cbuf   = (float*)(hchain + (size_t)(TC + 1) * B * H);
    int*            flags  = (int*)(cbuf + (size_t)B * H);     // NBLK*FSTR

    cast_f32_bf16<<<2048, 256, 0, stream>>>(Wih, wih, (G4 * H) / 8);
    cast_f32_bf16<<<2048, 256, 0, stream>>>(Whh, whh, (G4 * H) / 8);
    init_state<<<(B * H) / 256, 256, 0, stream>>>(h0, c0, hchain, cbuf);
    reset_flags<<<1, NBLK, 0, stream>>>(flags);

    for (int ci = 0; ci < NCH; ++ci) {
        gather_x<<<(TC * B) / 2, 256, 0, stream>>>(tgt, emb, xch, ci * TC);
        gemm_xproj<<<(TC * B / 128) * (G4 / 128), 256, 0, stream>>>(xch, wih, xproj);
        if (ci) copy_h<<<(B * H / 2) / 256, 256, 0, stream>>>(
                    hchain + (size_t)TC * B * H, hchain);
        int t0 = ci * TC;
        void* args[] = { (void*)&xproj, (void*)&whh, (void*)&bih, (void*)&bhh,
                         (void*)&hchain, (void*)&cbuf, (void*)&outputs,
                         (void*)&flags, (void*)&t0 };
        hipLaunchCooperativeKernel((void*)lstm_chunk, dim3(NBLK), dim3(512),
                                   args, 0, stream);
    }
    finalize<<<(B * H) / 256, 256, 0, stream>>>(outputs, cbuf, out_h, out_c);
}